// Round 6
// baseline (157.641 us; speedup 1.0000x reference)
//
#include <hip/hip_runtime.h>
#include <hip/hip_bf16.h>
#include <math.h>

// BarrierNet fused forward, v21.
// v20 (41.9us) won by amortizing block-invariant staging over 128 rows.
// Remaining dominant reducible cost: B-tile LDS re-read -- each wave reads
// the full 128KB staged B per 16 rows (2048 ds_read_b128/CU ~ 16-25k cy on
// the shared LDS pipe). v21: mt=2 -- each wave owns TWO 16-row A-sets
// (32 rows), so every Bf ds_read feeds 2 MFMAs -> per-row B reads halve.
// 256 thd/block, 4 waves x 32 rows = 128 rows/block, grid B/128 = 512
// -> 2 blocks/CU preserved (the inter-block overlap that beat all explicit
// pipelining in r17-r19). Occupancy halves (2 waves/SIMD) but per-wave ILP
// doubles. Tail: 2-way candidate split [0,24)/[24,46). All rs-indexed
// arrays fully unrolled (static indices, no scratch).

typedef unsigned int u32;
typedef unsigned long long u64;
typedef unsigned short u16;
typedef __attribute__((ext_vector_type(8))) short short8;   // 8 bf16 (MFMA A/B)
typedef __attribute__((ext_vector_type(4))) float f32x4;
typedef __attribute__((ext_vector_type(2))) float f32x2;
typedef __attribute__((ext_vector_type(4))) u32 u32x4;

union Frag { short8 v; u32 u[4]; u32x4 q; };

__device__ __forceinline__ u32 packbf(float a, float b) {
    float2 f2; f2.x = a; f2.y = b;
    __hip_bfloat162 h = __float22bfloat162_rn(f2);   // v_cvt_pk_bf16_f32
    union { __hip_bfloat162 h2; u32 u; } cv; cv.h2 = h;
    return cv.u;
}

__device__ const float OBX[8] = { 10.f, 7.07106781186547524f, 6.123234e-16f, -7.07106781186547524f,
                                 -10.f, -7.07106781186547524f, -1.8369702e-15f, 7.07106781186547524f };
__device__ const float OBY[8] = { 0.f, 7.07106781186547524f, 10.f, 7.07106781186547524f,
                                  1.2246468e-15f, -7.07106781186547524f, -10.f, -7.07106781186547524f };

// triu_indices(9,1) pairs packed as 4-bit nibbles in u64 immediates
#define PI0_ 0x2111111100000000ULL
#define PI1_ 0x5544443333322222ULL
#define PI2_ 0x7665ULL
#define PJ0_ 0x3876543287654321ULL
#define PJ1_ 0x7687658765487654ULL
#define PJ2_ 0x8878ULL
__device__ __forceinline__ int unpack4(u64 w0, u64 w1, u64 w2, int t) {
    u64 w = (t < 16) ? w0 : (t < 32) ? w1 : w2;
    return (int)((w >> ((t & 15) * 4)) & 15);
}

// ---------- prep: swizzle W2{1,2} (f32 [128][256]) into bf16 B-fragments ----------
// frag f = head*4096 + ks*512 + nt*64 + lane ; j=0..7:
//   W2h[n = nt*16 + (lane&15)][k = ks*32 + (lane>>4)*8 + j]
__global__ __launch_bounds__(256)
void prep_kernel(const float* __restrict__ W21, const float* __restrict__ W22,
                 u32* __restrict__ ws)
{
    int idx  = blockIdx.x * 256 + threadIdx.x;      // 0..8191
    int lane = idx & 63;
    int nt   = (idx >> 6) & 7;
    int ks   = (idx >> 9) & 7;
    int head = idx >> 12;
    const float* W = head ? W22 : W21;
    int n  = nt * 16 + (lane & 15);
    int k0 = ks * 32 + (lane >> 4) * 8;
    const float* s = W + n * 256 + k0;
    u32x4 o;
    o.x = packbf(s[0], s[1]);
    o.y = packbf(s[2], s[3]);
    o.z = packbf(s[4], s[5]);
    o.w = packbf(s[6], s[7]);
    __builtin_nontemporal_store(o, (u32x4*)ws + idx);
}

// ---------- fused: layer1 + two MFMA heads + QP tail ----------
__global__ __launch_bounds__(256)
void barriernet_kernel(const float* __restrict__ x,      // [B,8]
                       const float* __restrict__ meanp,  // [8]
                       const float* __restrict__ stdp,   // [8]
                       const float* __restrict__ W1,     // [256][8]
                       const float* __restrict__ b1,     // [256]
                       const float* __restrict__ b21,    // [128]
                       const float* __restrict__ W31,    // [2][128]
                       const float* __restrict__ b31,    // [2]
                       const float* __restrict__ b22,    // [128]
                       const float* __restrict__ W32,    // [2][128]
                       const float* __restrict__ b32,    // [2]
                       const u32* __restrict__ wsB,      // swizzled bf16 B-frags
                       float* __restrict__ out, int Btot)
{
    const int tid  = threadIdx.x;
    const int wave = tid >> 6;          // 0..3
    const int lane = tid & 63;
    const int q    = lane >> 4;
    const int m    = lane & 15;
    const int blockRow = blockIdx.x * 128;

    __shared__ u32x4 stage[2048];     // 32 KB; aliased by qC/res in the tail
    __shared__ float lds_p[128][4];   // 2 KB

    const f32x4* W1v = (const f32x4*)W1;
    const f32x4* b1v = (const f32x4*)b1;

    // ---- layer-1 for BOTH rowsets: A-fragments for all 8 K-steps (64 VGPR)
    Frag A[2][8];
    #pragma unroll
    for (int rs = 0; rs < 2; ++rs) {
        f32x4 xa0, xb0;
        {
            int R0 = blockRow + wave * 32 + rs * 16 + m;
            const f32x4* xv0 = (const f32x4*)(x + (R0 < Btot ? R0 : 0) * 8);
            xa0 = xv0[0]; xb0 = xv0[1];
        }
        #pragma unroll
        for (int ks = 0; ks < 8; ++ks) {
            int kb = ks * 32 + q * 8;
            f32x4 bA = b1v[kb >> 2];
            f32x4 bB = b1v[(kb >> 2) + 1];
            float h0[8];
            #pragma unroll
            for (int j = 0; j < 8; ++j) {
                f32x4 wa = W1v[(kb + j) * 2];
                f32x4 wb = W1v[(kb + j) * 2 + 1];
                float a0 = (j < 4) ? bA[j] : bB[j - 4];
                a0 = fmaf(wa.x, xa0.x, a0);
                a0 = fmaf(wa.y, xa0.y, a0);
                a0 = fmaf(wa.z, xa0.z, a0);
                a0 = fmaf(wa.w, xa0.w, a0);
                a0 = fmaf(wb.x, xb0.x, a0);
                a0 = fmaf(wb.y, xb0.y, a0);
                a0 = fmaf(wb.z, xb0.z, a0);
                a0 = fmaf(wb.w, xb0.w, a0);
                h0[j] = fmaxf(a0, 0.f);
            }
            #pragma unroll
            for (int t = 0; t < 4; ++t)
                A[rs][ks].u[t] = packbf(h0[2 * t], h0[2 * t + 1]);
        }
    }

    const u32x4* wsB4 = (const u32x4*)wsB;

    #pragma unroll 1
    for (int head = 0; head < 2; ++head) {
        const float* b2 = head ? b22 : b21;
        const float* W3 = head ? W32 : W31;
        const float* b3 = head ? b32 : b31;

        f32x4 acc[2][8];
        #pragma unroll
        for (int rs = 0; rs < 2; ++rs)
            #pragma unroll
            for (int nt = 0; nt < 8; ++nt) acc[rs][nt] = (f32x4){0.f, 0.f, 0.f, 0.f};

        #pragma unroll
        for (int half = 0; half < 2; ++half) {
            // coalesced cooperative stage: 2048 frags (32 KB) over 4 waves
            const u32x4* src = wsB4 + head * 4096 + half * 2048;
            #pragma unroll
            for (int i = 0; i < 8; ++i) {
                int fi = (wave * 8 + i) * 64 + lane;
                stage[fi] = src[fi];
            }
            __syncthreads();
            #pragma unroll
            for (int ksl = 0; ksl < 4; ++ksl) {
                const int ks = half * 4 + ksl;
                Frag Bf[8];
                #pragma unroll
                for (int nt = 0; nt < 8; ++nt)
                    Bf[nt].q = stage[ksl * 512 + nt * 64 + lane];
                #pragma unroll
                for (int nt = 0; nt < 8; ++nt) {
                    acc[0][nt] = __builtin_amdgcn_mfma_f32_16x16x32_bf16(A[0][ks].v, Bf[nt].v, acc[0][nt], 0, 0, 0);
                    acc[1][nt] = __builtin_amdgcn_mfma_f32_16x16x32_bf16(A[1][ks].v, Bf[nt].v, acc[1][nt], 0, 0, 0);
                }
            }
            __syncthreads();
        }

        // ---- epilogue: bias+relu+W3 dot, 16-lane reduce, LDS scatter (per rowset)
        #pragma unroll
        for (int rs = 0; rs < 2; ++rs) {
            float pr0[4], pr1[4];
            #pragma unroll
            for (int rg = 0; rg < 4; ++rg) { pr0[rg] = 0.f; pr1[rg] = 0.f; }
            #pragma unroll
            for (int nt = 0; nt < 8; ++nt) {
                int col = nt * 16 + m;
                float b2c = b2[col];
                float w0c = W3[col];
                float w1c = W3[128 + col];
                #pragma unroll
                for (int rg = 0; rg < 4; ++rg) {
                    float rv = fmaxf(acc[rs][nt][rg] + b2c, 0.f);
                    pr0[rg] = fmaf(rv, w0c, pr0[rg]);
                    pr1[rg] = fmaf(rv, w1c, pr1[rg]);
                }
            }
            #pragma unroll
            for (int rg = 0; rg < 4; ++rg) {
                float v0 = pr0[rg], v1 = pr1[rg];
                #pragma unroll
                for (int off = 1; off < 16; off <<= 1) {
                    v0 += __shfl_xor(v0, off, 64);
                    v1 += __shfl_xor(v1, off, 64);
                }
                pr0[rg] = v0; pr1[rg] = v1;
            }
            if (m == 0) {
                #pragma unroll
                for (int rg = 0; rg < 4; ++rg) {
                    int row = wave * 32 + rs * 16 + q * 4 + rg;
                    float a0 = pr0[rg] + b3[0];
                    float a1 = pr1[rg] + b3[1];
                    if (head == 0) {
                        lds_p[row][0] = a0;
                        lds_p[row][1] = a1;
                    } else {
                        lds_p[row][2] = 4.f / (1.f + __expf(-a0));
                        lds_p[row][3] = 4.f / (1.f + __expf(-a1));
                    }
                }
            }
        }
    }
    __syncthreads();

    // ================= QP tail (stage buffer reused) =================
    f32x4 (*qC)[128]  = (f32x4(*)[128])stage;             // 18 KB
    f32x4 (*res)[128] = (f32x4(*)[128])(stage + 1152);    // 2 KB, after qC

    const int rq   = tid & 127;         // row within block (0..127)
    const int part = tid >> 7;          // 0..1
    const int R    = blockRow + rq;
    float p0 = lds_p[rq][0];
    float p1 = lds_p[rq][1];

    if (part == 0) {
        float s0 = lds_p[rq][2];
        float s1 = lds_p[rq][3];
        float xr[8];
        const float* xp = x + (R < Btot ? R : 0) * 8;
        #pragma unroll
        for (int c = 0; c < 8; ++c) xr[c] = fmaf(xp[c], stdp[c], meanp[c]);
        float px = xr[0], py = xr[1], th = xr[2], v = xr[3];
        float ox = xr[4], oy = xr[5], oth = xr[6], ov = xr[7];
        float st = __sinf(th),  ct = __cosf(th);
        float so = __sinf(oth), co = __cosf(oth);
        float vs = v * st, vc = v * ct;
        float sps = s0 + s1, ss = s0 * s1;
        float Lf2b = 2.f * v * v;
        #pragma unroll 1
        for (int k = 0; k < 8; ++k) {
            float dx = px - OBX[k], dy = py - OBY[k];
            float bar  = dx * dx + dy * dy - 0.64f;
            float bdot = 2.f * dx * vc + 2.f * dy * vs;
            float gx = 2.f * dx * vs - 2.f * dy * vc;
            float gy = -(2.f * dx * ct + 2.f * dy * st);
            float hk = Lf2b + sps * bdot + ss * bar;
            float ht = hk + 1e-6f * (1.f + fabsf(hk));
            qC[k][rq] = (f32x4){gx, gy, hk, ht};
        }
        {
            float dxo = px - ox, dyo = py - oy;
            float bar_o  = dxo * dxo + dyo * dyo - 0.25f;
            float bdot_o = 2.f * dxo * (vc - ov * co) + 2.f * dyo * (vs - ov * so);
            float Lf2b_o = 2.f * (v * v + ov * ov + 2.f * v * ov * __cosf(th - oth));
            float gx = 2.f * dxo * vs - 2.f * dyo * vc;
            float gy = -(2.f * dxo * ct + 2.f * dyo * st);
            float hk = Lf2b_o + sps * bdot_o + ss * bar_o;
            float ht = hk + 1e-6f * (1.f + fabsf(hk));
            qC[8][rq] = (f32x4){gx, gy, hk, ht};
        }
    }
    __syncthreads();

    // preload the 9 constraints into NAMED registers
    const f32x4 C0 = qC[0][rq], C1 = qC[1][rq], C2 = qC[2][rq];
    const f32x4 C3 = qC[3][rq], C4 = qC[4][rq], C5 = qC[5][rq];
    const f32x4 C6 = qC[6][rq], C7 = qC[7][rq], C8 = qC[8][rq];

    // candidates: 0 unconstrained, 1..9 singles, 10..45 pairs (triu order)
    // 2-way ordered split: [0,24) [24,46)
    const int c0i = (part == 0) ? 0  : 24;
    const int c1i = (part == 0) ? 24 : 46;
    float bobj = INFINITY;
    float bzx = -p0, bzy = -p1;     // argmin of all-inf -> index 0 -> z0
    #pragma unroll 2
    for (int c = c0i; c < c1i; ++c) {
        float zx, zy;
        bool pre;
        if (c == 0) {
            zx = -p0; zy = -p1; pre = true;
        } else if (c <= 9) {
            f32x4 g = qC[c - 1][rq];                 // one ds_read_b128
            float gg  = g.x * g.x + g.y * g.y;
            float lam = (-(g.x * p0 + g.y * p1) - g.z) / (gg + 1e-12f);
            zx = -p0 - lam * g.x;
            zy = -p1 - lam * g.y;
            pre = (lam >= -1e-8f);
        } else {
            int t = c - 10;
            int pi = unpack4(PI0_, PI1_, PI2_, t);   // scalar, no memory
            int pj = unpack4(PJ0_, PJ1_, PJ2_, t);
            f32x4 gi = qC[pi][rq];                   // two ds_read_b128
            f32x4 gj = qC[pj][rq];
            float det = gi.x * gj.y - gi.y * gj.x;
            bool dok = fabsf(det) > 1e-9f;
            float ds = dok ? det : 1.0f;
            float inv = 1.0f / ds;
            zx = (gi.z * gj.y - gj.z * gi.y) * inv;
            zy = (gi.x * gj.z - gj.x * gi.z) * inv;
            float rx = -(zx + p0), ry = -(zy + p1);
            float li = (gj.y * rx - gj.x * ry) * inv;
            float lj = (gi.x * ry - gi.y * rx) * inv;
            pre = dok && (li >= -1e-8f) && (lj >= -1e-8f);
        }
        bool ok = pre;
        ok = ok && (zx * C0.x + zy * C0.y <= C0.w);
        ok = ok && (zx * C1.x + zy * C1.y <= C1.w);
        ok = ok && (zx * C2.x + zy * C2.y <= C2.w);
        ok = ok && (zx * C3.x + zy * C3.y <= C3.w);
        ok = ok && (zx * C4.x + zy * C4.y <= C4.w);
        ok = ok && (zx * C5.x + zy * C5.y <= C5.w);
        ok = ok && (zx * C6.x + zy * C6.y <= C6.w);
        ok = ok && (zx * C7.x + zy * C7.y <= C7.w);
        ok = ok && (zx * C8.x + zy * C8.y <= C8.w);
        float obj = 0.5f * (zx * zx + zy * zy) + zx * p0 + zy * p1;
        if (ok && obj < bobj) { bobj = obj; bzx = zx; bzy = zy; }
    }

    if (part) {
        res[0][rq] = (f32x4){bobj, bzx, bzy, 0.f};
    }
    __syncthreads();
    if (part == 0) {
        f32x4 r = res[0][rq];
        if (r.x < bobj) { bobj = r.x; bzx = r.y; bzy = r.z; }  // strict <, ordered
        if (R < Btot) {
            f32x2 o2; o2.x = bzx; o2.y = bzy;
            ((f32x2*)out)[R] = o2;
        }
    }
}

extern "C" void kernel_launch(void* const* d_in, const int* in_sizes, int n_in,
                              void* d_out, int out_size, void* d_ws, size_t ws_size,
                              hipStream_t stream) {
    const float* x    = (const float*)d_in[0];
    const float* mean = (const float*)d_in[1];
    const float* stdv = (const float*)d_in[2];
    const float* W1   = (const float*)d_in[3];
    const float* b1   = (const float*)d_in[4];
    const float* W21  = (const float*)d_in[5];
    const float* b21  = (const float*)d_in[6];
    const float* W31  = (const float*)d_in[7];
    const float* b31  = (const float*)d_in[8];
    const float* W22  = (const float*)d_in[9];
    const float* b22  = (const float*)d_in[10];
    const float* W32  = (const float*)d_in[11];
    const float* b32  = (const float*)d_in[12];
    int B = in_sizes[0] / 8;
    float* out = (float*)d_out;
    u32* ws = (u32*)d_ws;

    hipLaunchKernelGGL(prep_kernel, dim3(32), dim3(256), 0, stream, W21, W22, ws);

    hipLaunchKernelGGL(barriernet_kernel, dim3((B + 127) / 128), dim3(256), 0, stream,
                       x, mean, stdv, W1, b1, b21, W31, b31, b22, W32, b32,
                       ws, out, B);
}

// Round 7
// 141.008 us; speedup vs baseline: 1.1180x; 1.1180x over previous
//
#include <hip/hip_runtime.h>
#include <hip/hip_bf16.h>
#include <math.h>

// BarrierNet fused forward, v22.
// v21 (mt=2 in regs) spilled exactly as feared (VGPR 256, WRITE 60MB, 85us).
// v20 (41.9us) analysis: VGPR 56, LDS 34KB -> the CU could host 32 waves
// (4 blocks x 8 waves), but grid 512 = 2 blocks/CU supplies only 16.
// Occupancy is GRID-limited. v22: head-split waves. Block = 512 thd / 64
// rows, grid 1024 = 4 blocks/CU = 32 waves/CU. Wave pair (2w,2w+1) owns
// row-tile w; wave&1 selects the head. Per wave: 64 MFMA, 64 B-ds_reads,
// A[8]+acc[8] (v20-small footprint). Staging phase = ks-pair x BOTH heads
// (32KB), 4 phases. Costs accepted: 2x per-CU staging, 2x layer-1
// (+~2.4k cy/SIMD). Gains: 2x TLP for the latency-bound core + 8-way QP
// tail split (serial chain 24 -> ~6 candidates).

typedef unsigned int u32;
typedef unsigned long long u64;
typedef unsigned short u16;
typedef __attribute__((ext_vector_type(8))) short short8;   // 8 bf16 (MFMA A/B)
typedef __attribute__((ext_vector_type(4))) float f32x4;
typedef __attribute__((ext_vector_type(2))) float f32x2;
typedef __attribute__((ext_vector_type(4))) u32 u32x4;

union Frag { short8 v; u32 u[4]; u32x4 q; };

__device__ __forceinline__ u32 packbf(float a, float b) {
    float2 f2; f2.x = a; f2.y = b;
    __hip_bfloat162 h = __float22bfloat162_rn(f2);   // v_cvt_pk_bf16_f32
    union { __hip_bfloat162 h2; u32 u; } cv; cv.h2 = h;
    return cv.u;
}

__device__ const float OBX[8] = { 10.f, 7.07106781186547524f, 6.123234e-16f, -7.07106781186547524f,
                                 -10.f, -7.07106781186547524f, -1.8369702e-15f, 7.07106781186547524f };
__device__ const float OBY[8] = { 0.f, 7.07106781186547524f, 10.f, 7.07106781186547524f,
                                  1.2246468e-15f, -7.07106781186547524f, -10.f, -7.07106781186547524f };

// triu_indices(9,1) pairs packed as 4-bit nibbles in u64 immediates
#define PI0_ 0x2111111100000000ULL
#define PI1_ 0x5544443333322222ULL
#define PI2_ 0x7665ULL
#define PJ0_ 0x3876543287654321ULL
#define PJ1_ 0x7687658765487654ULL
#define PJ2_ 0x8878ULL
__device__ __forceinline__ int unpack4(u64 w0, u64 w1, u64 w2, int t) {
    u64 w = (t < 16) ? w0 : (t < 32) ? w1 : w2;
    return (int)((w >> ((t & 15) * 4)) & 15);
}

// ---------- prep: swizzle W2{1,2} (f32 [128][256]) into bf16 B-fragments ----------
// frag f = head*4096 + ks*512 + nt*64 + lane ; j=0..7:
//   W2h[n = nt*16 + (lane&15)][k = ks*32 + (lane>>4)*8 + j]
__global__ __launch_bounds__(256)
void prep_kernel(const float* __restrict__ W21, const float* __restrict__ W22,
                 u32* __restrict__ ws)
{
    int idx  = blockIdx.x * 256 + threadIdx.x;      // 0..8191
    int lane = idx & 63;
    int nt   = (idx >> 6) & 7;
    int ks   = (idx >> 9) & 7;
    int head = idx >> 12;
    const float* W = head ? W22 : W21;
    int n  = nt * 16 + (lane & 15);
    int k0 = ks * 32 + (lane >> 4) * 8;
    const float* s = W + n * 256 + k0;
    u32x4 o;
    o.x = packbf(s[0], s[1]);
    o.y = packbf(s[2], s[3]);
    o.z = packbf(s[4], s[5]);
    o.w = packbf(s[6], s[7]);
    __builtin_nontemporal_store(o, (u32x4*)ws + idx);
}

// ---------- fused: layer1 + head-split MFMA + QP tail ----------
__global__ __launch_bounds__(512)
void barriernet_kernel(const float* __restrict__ x,      // [B,8]
                       const float* __restrict__ meanp,  // [8]
                       const float* __restrict__ stdp,   // [8]
                       const float* __restrict__ W1,     // [256][8]
                       const float* __restrict__ b1,     // [256]
                       const float* __restrict__ b21,    // [128]
                       const float* __restrict__ W31,    // [2][128]
                       const float* __restrict__ b31,    // [2]
                       const float* __restrict__ b22,    // [128]
                       const float* __restrict__ W32,    // [2][128]
                       const float* __restrict__ b32,    // [2]
                       const u32* __restrict__ wsB,      // swizzled bf16 B-frags
                       float* __restrict__ out, int Btot)
{
    const int tid  = threadIdx.x;
    const int wave = tid >> 6;          // 0..7
    const int lane = tid & 63;
    const int q    = lane >> 4;
    const int m    = lane & 15;
    const int rowtile = wave >> 1;      // 0..3 (16 rows each)
    const int headw   = wave & 1;       // this wave's head
    const int blockRow = blockIdx.x * 64;

    __shared__ u32x4 stage[2048];     // 32 KB; aliased by qC/res in the tail
    __shared__ float lds_p[64][4];    // 1 KB

    f32x4 xa0, xb0;
    {
        int R0 = blockRow + rowtile * 16 + m;
        const f32x4* xv0 = (const f32x4*)(x + (R0 < Btot ? R0 : 0) * 8);
        xa0 = xv0[0]; xb0 = xv0[1];
    }

    const f32x4* W1v = (const f32x4*)W1;
    const f32x4* b1v = (const f32x4*)b1;

    // ---- layer-1: A-fragments for all 8 K-steps (32 VGPR)
    // (computed by both waves of a row-pair -- duplication accepted)
    Frag A[8];
    #pragma unroll
    for (int ks = 0; ks < 8; ++ks) {
        int kb = ks * 32 + q * 8;
        f32x4 bA = b1v[kb >> 2];
        f32x4 bB = b1v[(kb >> 2) + 1];
        float h0[8];
        #pragma unroll
        for (int j = 0; j < 8; ++j) {
            f32x4 wa = W1v[(kb + j) * 2];
            f32x4 wb = W1v[(kb + j) * 2 + 1];
            float a0 = (j < 4) ? bA[j] : bB[j - 4];
            a0 = fmaf(wa.x, xa0.x, a0);
            a0 = fmaf(wa.y, xa0.y, a0);
            a0 = fmaf(wa.z, xa0.z, a0);
            a0 = fmaf(wa.w, xa0.w, a0);
            a0 = fmaf(wb.x, xb0.x, a0);
            a0 = fmaf(wb.y, xb0.y, a0);
            a0 = fmaf(wb.z, xb0.z, a0);
            a0 = fmaf(wb.w, xb0.w, a0);
            h0[j] = fmaxf(a0, 0.f);
        }
        #pragma unroll
        for (int t = 0; t < 4; ++t)
            A[ks].u[t] = packbf(h0[2 * t], h0[2 * t + 1]);
    }

    const u32x4* wsB4 = (const u32x4*)wsB;

    // ---- GEMM: this wave computes ONE head for its 16 rows
    const float* b2 = headw ? b22 : b21;
    const float* W3 = headw ? W32 : W31;
    const float* b3 = headw ? b32 : b31;

    f32x4 acc[8];
    #pragma unroll
    for (int nt = 0; nt < 8; ++nt) acc[nt] = (f32x4){0.f, 0.f, 0.f, 0.f};

    const int hb = headw * 1024;      // this wave's half of stage

    #pragma unroll
    for (int p = 0; p < 4; ++p) {
        // stage ks-pair {2p,2p+1} of BOTH heads: 2048 frags (32 KB), 4/thread
        #pragma unroll
        for (int h = 0; h < 2; ++h) {
            #pragma unroll
            for (int i = 0; i < 2; ++i) {
                int j = i * 512 + tid;
                stage[h * 1024 + j] = wsB4[h * 4096 + p * 1024 + j];
            }
        }
        __syncthreads();
        #pragma unroll
        for (int ksl = 0; ksl < 2; ++ksl) {
            const int ks = p * 2 + ksl;
            Frag Bf[8];
            #pragma unroll
            for (int nt = 0; nt < 8; ++nt)
                Bf[nt].q = stage[hb + ksl * 512 + nt * 64 + lane];
            #pragma unroll
            for (int nt = 0; nt < 8; ++nt)
                acc[nt] = __builtin_amdgcn_mfma_f32_16x16x32_bf16(A[ks].v, Bf[nt].v, acc[nt], 0, 0, 0);
        }
        __syncthreads();
    }

    // ---- epilogue: bias+relu+W3 dot, 16-lane reduce, LDS scatter
    {
        float pr0[4], pr1[4];
        #pragma unroll
        for (int rg = 0; rg < 4; ++rg) { pr0[rg] = 0.f; pr1[rg] = 0.f; }
        #pragma unroll
        for (int nt = 0; nt < 8; ++nt) {
            int col = nt * 16 + m;
            float b2c = b2[col];
            float w0c = W3[col];
            float w1c = W3[128 + col];
            #pragma unroll
            for (int rg = 0; rg < 4; ++rg) {
                float rv = fmaxf(acc[nt][rg] + b2c, 0.f);
                pr0[rg] = fmaf(rv, w0c, pr0[rg]);
                pr1[rg] = fmaf(rv, w1c, pr1[rg]);
            }
        }
        #pragma unroll
        for (int rg = 0; rg < 4; ++rg) {
            float v0 = pr0[rg], v1 = pr1[rg];
            #pragma unroll
            for (int off = 1; off < 16; off <<= 1) {
                v0 += __shfl_xor(v0, off, 64);
                v1 += __shfl_xor(v1, off, 64);
            }
            pr0[rg] = v0; pr1[rg] = v1;
        }
        if (m == 0) {
            #pragma unroll
            for (int rg = 0; rg < 4; ++rg) {
                int row = rowtile * 16 + q * 4 + rg;
                float a0 = pr0[rg] + b3[0];
                float a1 = pr1[rg] + b3[1];
                if (headw == 0) {
                    lds_p[row][0] = a0;
                    lds_p[row][1] = a1;
                } else {
                    lds_p[row][2] = 4.f / (1.f + __expf(-a0));
                    lds_p[row][3] = 4.f / (1.f + __expf(-a1));
                }
            }
        }
    }
    __syncthreads();

    // ================= QP tail (stage buffer reused) =================
    f32x4 (*qC)[64]  = (f32x4(*)[64])stage;           // 9 KB
    f32x4 (*res)[64] = (f32x4(*)[64])(stage + 576);   // 7 KB, after qC

    const int rq   = tid & 63;          // row within block (0..63)
    const int part = tid >> 6;          // 0..7
    const int R    = blockRow + rq;
    float p0 = lds_p[rq][0];
    float p1 = lds_p[rq][1];

    if (part == 0) {
        float s0 = lds_p[rq][2];
        float s1 = lds_p[rq][3];
        float xr[8];
        const float* xp = x + (R < Btot ? R : 0) * 8;
        #pragma unroll
        for (int c = 0; c < 8; ++c) xr[c] = fmaf(xp[c], stdp[c], meanp[c]);
        float px = xr[0], py = xr[1], th = xr[2], v = xr[3];
        float ox = xr[4], oy = xr[5], oth = xr[6], ov = xr[7];
        float st = __sinf(th),  ct = __cosf(th);
        float so = __sinf(oth), co = __cosf(oth);
        float vs = v * st, vc = v * ct;
        float sps = s0 + s1, ss = s0 * s1;
        float Lf2b = 2.f * v * v;
        #pragma unroll 1
        for (int k = 0; k < 8; ++k) {
            float dx = px - OBX[k], dy = py - OBY[k];
            float bar  = dx * dx + dy * dy - 0.64f;
            float bdot = 2.f * dx * vc + 2.f * dy * vs;
            float gx = 2.f * dx * vs - 2.f * dy * vc;
            float gy = -(2.f * dx * ct + 2.f * dy * st);
            float hk = Lf2b + sps * bdot + ss * bar;
            float ht = hk + 1e-6f * (1.f + fabsf(hk));
            qC[k][rq] = (f32x4){gx, gy, hk, ht};
        }
        {
            float dxo = px - ox, dyo = py - oy;
            float bar_o  = dxo * dxo + dyo * dyo - 0.25f;
            float bdot_o = 2.f * dxo * (vc - ov * co) + 2.f * dyo * (vs - ov * so);
            float Lf2b_o = 2.f * (v * v + ov * ov + 2.f * v * ov * __cosf(th - oth));
            float gx = 2.f * dxo * vs - 2.f * dyo * vc;
            float gy = -(2.f * dxo * ct + 2.f * dyo * st);
            float hk = Lf2b_o + sps * bdot_o + ss * bar_o;
            float ht = hk + 1e-6f * (1.f + fabsf(hk));
            qC[8][rq] = (f32x4){gx, gy, hk, ht};
        }
    }
    __syncthreads();

    // preload the 9 constraints into NAMED registers
    const f32x4 C0 = qC[0][rq], C1 = qC[1][rq], C2 = qC[2][rq];
    const f32x4 C3 = qC[3][rq], C4 = qC[4][rq], C5 = qC[5][rq];
    const f32x4 C6 = qC[6][rq], C7 = qC[7][rq], C8 = qC[8][rq];

    // candidates: 0 unconstrained, 1..9 singles, 10..45 pairs (triu order)
    // 8-way ordered split, boundaries packed 6b each in a u64:
    // {0,7,13,19,25,31,36,41,46}
    const u64 BNDS = (7ULL << 6) | (13ULL << 12) | (19ULL << 18) | (25ULL << 24)
                   | (31ULL << 30) | (36ULL << 36) | (41ULL << 42) | (46ULL << 48);
    const int c0i = (int)((BNDS >> (6 * part)) & 63);
    const int c1i = (int)((BNDS >> (6 * part + 6)) & 63);
    float bobj = INFINITY;
    float bzx = -p0, bzy = -p1;     // argmin of all-inf -> index 0 -> z0
    #pragma unroll 2
    for (int c = c0i; c < c1i; ++c) {
        float zx, zy;
        bool pre;
        if (c == 0) {
            zx = -p0; zy = -p1; pre = true;
        } else if (c <= 9) {
            f32x4 g = qC[c - 1][rq];                 // one ds_read_b128
            float gg  = g.x * g.x + g.y * g.y;
            float lam = (-(g.x * p0 + g.y * p1) - g.z) / (gg + 1e-12f);
            zx = -p0 - lam * g.x;
            zy = -p1 - lam * g.y;
            pre = (lam >= -1e-8f);
        } else {
            int t = c - 10;
            int pi = unpack4(PI0_, PI1_, PI2_, t);   // scalar, no memory
            int pj = unpack4(PJ0_, PJ1_, PJ2_, t);
            f32x4 gi = qC[pi][rq];                   // two ds_read_b128
            f32x4 gj = qC[pj][rq];
            float det = gi.x * gj.y - gi.y * gj.x;
            bool dok = fabsf(det) > 1e-9f;
            float ds = dok ? det : 1.0f;
            float inv = 1.0f / ds;
            zx = (gi.z * gj.y - gj.z * gi.y) * inv;
            zy = (gi.x * gj.z - gj.x * gi.z) * inv;
            float rx = -(zx + p0), ry = -(zy + p1);
            float li = (gj.y * rx - gj.x * ry) * inv;
            float lj = (gi.x * ry - gi.y * rx) * inv;
            pre = dok && (li >= -1e-8f) && (lj >= -1e-8f);
        }
        bool ok = pre;
        ok = ok && (zx * C0.x + zy * C0.y <= C0.w);
        ok = ok && (zx * C1.x + zy * C1.y <= C1.w);
        ok = ok && (zx * C2.x + zy * C2.y <= C2.w);
        ok = ok && (zx * C3.x + zy * C3.y <= C3.w);
        ok = ok && (zx * C4.x + zy * C4.y <= C4.w);
        ok = ok && (zx * C5.x + zy * C5.y <= C5.w);
        ok = ok && (zx * C6.x + zy * C6.y <= C6.w);
        ok = ok && (zx * C7.x + zy * C7.y <= C7.w);
        ok = ok && (zx * C8.x + zy * C8.y <= C8.w);
        float obj = 0.5f * (zx * zx + zy * zy) + zx * p0 + zy * p1;
        if (ok && obj < bobj) { bobj = obj; bzx = zx; bzy = zy; }
    }

    if (part) {
        res[part - 1][rq] = (f32x4){bobj, bzx, bzy, 0.f};
    }
    __syncthreads();
    if (part == 0) {
        #pragma unroll
        for (int pp = 0; pp < 7; ++pp) {
            f32x4 r = res[pp][rq];
            if (r.x < bobj) { bobj = r.x; bzx = r.y; bzy = r.z; }  // strict <, ordered
        }
        if (R < Btot) {
            f32x2 o2; o2.x = bzx; o2.y = bzy;
            ((f32x2*)out)[R] = o2;
        }
    }
}

extern "C" void kernel_launch(void* const* d_in, const int* in_sizes, int n_in,
                              void* d_out, int out_size, void* d_ws, size_t ws_size,
                              hipStream_t stream) {
    const float* x    = (const float*)d_in[0];
    const float* mean = (const float*)d_in[1];
    const float* stdv = (const float*)d_in[2];
    const float* W1   = (const float*)d_in[3];
    const float* b1   = (const float*)d_in[4];
    const float* W21  = (const float*)d_in[5];
    const float* b21  = (const float*)d_in[6];
    const float* W31  = (const float*)d_in[7];
    const float* b31  = (const float*)d_in[8];
    const float* W22  = (const float*)d_in[9];
    const float* b22  = (const float*)d_in[10];
    const float* W32  = (const float*)d_in[11];
    const float* b32  = (const float*)d_in[12];
    int B = in_sizes[0] / 8;
    float* out = (float*)d_out;
    u32* ws = (u32*)d_ws;

    hipLaunchKernelGGL(prep_kernel, dim3(32), dim3(256), 0, stream, W21, W22, ws);

    hipLaunchKernelGGL(barriernet_kernel, dim3((B + 63) / 64), dim3(512), 0, stream,
                       x, mean, stdv, W1, b1, b21, W31, b31, b22, W32, b32,
                       ws, out, B);
}

// Round 8
// 117.418 us; speedup vs baseline: 1.3426x; 1.2009x over previous
//
#include <hip/hip_runtime.h>
#include <hip/hip_bf16.h>
#include <math.h>

// BarrierNet fused forward, v23.
// v22 post-mortem: more waves under the same stage/barrier rhythm made it
// WORSE (72us) -- the lockstep barrier structure is the poison, not wave
// count. v23 removes the rhythm: B (both heads, 128 KB bf16 frags) fits in
// LDS PERSISTENTLY. Block = 1024 thd / 256 rows, grid 256 = 1 block/CU.
// One-shot global_load_lds DMA fill (flies under layer-1), ONE barrier,
// then a barrier-free GEMM: per wave 2 heads x 8 ks x (8 ds_read_b128 +
// 8 MFMA) from persistent B, waves free-running (setprio(1) around MFMA
// bursts -- the unsynced regime where it measured +4-7%). Staging L2
// traffic halves (32 MB total), barriers 10 -> 2, ds_writes -> DMA.
// Tail = v20's 4-way split; qC/res alias the dead B buffer.

typedef unsigned int u32;
typedef unsigned long long u64;
typedef unsigned short u16;
typedef __attribute__((ext_vector_type(8))) short short8;   // 8 bf16 (MFMA A/B)
typedef __attribute__((ext_vector_type(4))) float f32x4;
typedef __attribute__((ext_vector_type(2))) float f32x2;
typedef __attribute__((ext_vector_type(4))) u32 u32x4;

union Frag { short8 v; u32 u[4]; u32x4 q; };

// async global->LDS DMA, 16B per lane; lds ptr must be wave-uniform
// (HW writes lane L's 16B at ldsbase + L*16)
#define DMA16(gp, lp)                                                        \
    __builtin_amdgcn_global_load_lds(                                        \
        (const __attribute__((address_space(1))) void*)(gp),                 \
        (__attribute__((address_space(3))) void*)(lp), 16, 0, 0)

__device__ __forceinline__ u32 packbf(float a, float b) {
    float2 f2; f2.x = a; f2.y = b;
    __hip_bfloat162 h = __float22bfloat162_rn(f2);   // v_cvt_pk_bf16_f32
    union { __hip_bfloat162 h2; u32 u; } cv; cv.h2 = h;
    return cv.u;
}

__device__ const float OBX[8] = { 10.f, 7.07106781186547524f, 6.123234e-16f, -7.07106781186547524f,
                                 -10.f, -7.07106781186547524f, -1.8369702e-15f, 7.07106781186547524f };
__device__ const float OBY[8] = { 0.f, 7.07106781186547524f, 10.f, 7.07106781186547524f,
                                  1.2246468e-15f, -7.07106781186547524f, -10.f, -7.07106781186547524f };

// triu_indices(9,1) pairs packed as 4-bit nibbles in u64 immediates
#define PI0_ 0x2111111100000000ULL
#define PI1_ 0x5544443333322222ULL
#define PI2_ 0x7665ULL
#define PJ0_ 0x3876543287654321ULL
#define PJ1_ 0x7687658765487654ULL
#define PJ2_ 0x8878ULL
__device__ __forceinline__ int unpack4(u64 w0, u64 w1, u64 w2, int t) {
    u64 w = (t < 16) ? w0 : (t < 32) ? w1 : w2;
    return (int)((w >> ((t & 15) * 4)) & 15);
}

// ---------- prep: swizzle W2{1,2} (f32 [128][256]) into bf16 B-fragments ----------
// frag f = head*4096 + ks*512 + nt*64 + lane ; j=0..7:
//   W2h[n = nt*16 + (lane&15)][k = ks*32 + (lane>>4)*8 + j]
__global__ __launch_bounds__(256)
void prep_kernel(const float* __restrict__ W21, const float* __restrict__ W22,
                 u32* __restrict__ ws)
{
    int idx  = blockIdx.x * 256 + threadIdx.x;      // 0..8191
    int lane = idx & 63;
    int nt   = (idx >> 6) & 7;
    int ks   = (idx >> 9) & 7;
    int head = idx >> 12;
    const float* W = head ? W22 : W21;
    int n  = nt * 16 + (lane & 15);
    int k0 = ks * 32 + (lane >> 4) * 8;
    const float* s = W + n * 256 + k0;
    u32x4 o;
    o.x = packbf(s[0], s[1]);
    o.y = packbf(s[2], s[3]);
    o.z = packbf(s[4], s[5]);
    o.w = packbf(s[6], s[7]);
    __builtin_nontemporal_store(o, (u32x4*)ws + idx);
}

// ---------- fused: layer1 + persistent-B MFMA + QP tail ----------
__global__ __launch_bounds__(1024)
void barriernet_kernel(const float* __restrict__ x,      // [B,8]
                       const float* __restrict__ meanp,  // [8]
                       const float* __restrict__ stdp,   // [8]
                       const float* __restrict__ W1,     // [256][8]
                       const float* __restrict__ b1,     // [256]
                       const float* __restrict__ b21,    // [128]
                       const float* __restrict__ W31,    // [2][128]
                       const float* __restrict__ b31,    // [2]
                       const float* __restrict__ b22,    // [128]
                       const float* __restrict__ W32,    // [2][128]
                       const float* __restrict__ b32,    // [2]
                       const u32* __restrict__ wsB,      // swizzled bf16 B-frags
                       float* __restrict__ out, int Btot)
{
    const int tid  = threadIdx.x;
    const int wave = tid >> 6;          // 0..15
    const int lane = tid & 63;
    const int q    = lane >> 4;
    const int m    = lane & 15;
    const int blockRow = blockIdx.x * 256;

    __shared__ u32x4 Bbuf[8192];      // 128 KB persistent B (both heads); tail aliases
    __shared__ float lds_p[256][4];   // 4 KB

    const u32x4* wsB4 = (const u32x4*)wsB;

    // ---- one-shot DMA fill of the full B (8192 frags); flies under layer-1
    {
        const u32x4* g0 = wsB4 + wave * 512 + lane;
        u32x4* l0 = Bbuf + wave * 512;            // wave-uniform base
        #pragma unroll
        for (int i = 0; i < 8; ++i)
            DMA16(g0 + i * 64, l0 + i * 64);
    }

    f32x4 xa0, xb0;
    {
        int R0 = blockRow + wave * 16 + m;
        const f32x4* xv0 = (const f32x4*)(x + (R0 < Btot ? R0 : 0) * 8);
        xa0 = xv0[0]; xb0 = xv0[1];
    }

    const f32x4* W1v = (const f32x4*)W1;
    const f32x4* b1v = (const f32x4*)b1;

    // ---- layer-1 ONCE: A-fragments for all 8 K-steps (32 VGPR)
    Frag A[8];
    #pragma unroll
    for (int ks = 0; ks < 8; ++ks) {
        int kb = ks * 32 + q * 8;
        f32x4 bA = b1v[kb >> 2];
        f32x4 bB = b1v[(kb >> 2) + 1];
        float h0[8];
        #pragma unroll
        for (int j = 0; j < 8; ++j) {
            f32x4 wa = W1v[(kb + j) * 2];
            f32x4 wb = W1v[(kb + j) * 2 + 1];
            float a0 = (j < 4) ? bA[j] : bB[j - 4];
            a0 = fmaf(wa.x, xa0.x, a0);
            a0 = fmaf(wa.y, xa0.y, a0);
            a0 = fmaf(wa.z, xa0.z, a0);
            a0 = fmaf(wa.w, xa0.w, a0);
            a0 = fmaf(wb.x, xb0.x, a0);
            a0 = fmaf(wb.y, xb0.y, a0);
            a0 = fmaf(wb.z, xb0.z, a0);
            a0 = fmaf(wb.w, xb0.w, a0);
            h0[j] = fmaxf(a0, 0.f);
        }
        #pragma unroll
        for (int t = 0; t < 4; ++t)
            A[ks].u[t] = packbf(h0[2 * t], h0[2 * t + 1]);
    }

    // ---- ONE barrier: DMA drained (vmcnt(0) before s_barrier) + all waves here
    __syncthreads();

    // ---- barrier-free GEMM over persistent B: both heads
    #pragma unroll 1
    for (int head = 0; head < 2; ++head) {
        const float* b2 = head ? b22 : b21;
        const float* W3 = head ? W32 : W31;
        const float* b3 = head ? b32 : b31;

        f32x4 acc[8];
        #pragma unroll
        for (int nt = 0; nt < 8; ++nt) acc[nt] = (f32x4){0.f, 0.f, 0.f, 0.f};

        const u32x4* hB = Bbuf + head * 4096;
        #pragma unroll
        for (int ks = 0; ks < 8; ++ks) {
            Frag Bf[8];
            #pragma unroll
            for (int nt = 0; nt < 8; ++nt)
                Bf[nt].q = hB[ks * 512 + nt * 64 + lane];
            __builtin_amdgcn_s_setprio(1);
            #pragma unroll
            for (int nt = 0; nt < 8; ++nt)
                acc[nt] = __builtin_amdgcn_mfma_f32_16x16x32_bf16(A[ks].v, Bf[nt].v, acc[nt], 0, 0, 0);
            __builtin_amdgcn_s_setprio(0);
        }

        // ---- epilogue: bias+relu+W3 dot, 16-lane reduce, LDS scatter
        float pr0[4], pr1[4];
        #pragma unroll
        for (int rg = 0; rg < 4; ++rg) { pr0[rg] = 0.f; pr1[rg] = 0.f; }
        #pragma unroll
        for (int nt = 0; nt < 8; ++nt) {
            int col = nt * 16 + m;
            float b2c = b2[col];
            float w0c = W3[col];
            float w1c = W3[128 + col];
            #pragma unroll
            for (int rg = 0; rg < 4; ++rg) {
                float rv = fmaxf(acc[nt][rg] + b2c, 0.f);
                pr0[rg] = fmaf(rv, w0c, pr0[rg]);
                pr1[rg] = fmaf(rv, w1c, pr1[rg]);
            }
        }
        #pragma unroll
        for (int rg = 0; rg < 4; ++rg) {
            float v0 = pr0[rg], v1 = pr1[rg];
            #pragma unroll
            for (int off = 1; off < 16; off <<= 1) {
                v0 += __shfl_xor(v0, off, 64);
                v1 += __shfl_xor(v1, off, 64);
            }
            pr0[rg] = v0; pr1[rg] = v1;
        }
        if (m == 0) {
            #pragma unroll
            for (int rg = 0; rg < 4; ++rg) {
                int row = wave * 16 + q * 4 + rg;
                float a0 = pr0[rg] + b3[0];
                float a1 = pr1[rg] + b3[1];
                if (head == 0) {
                    lds_p[row][0] = a0;
                    lds_p[row][1] = a1;
                } else {
                    lds_p[row][2] = 4.f / (1.f + __expf(-a0));
                    lds_p[row][3] = 4.f / (1.f + __expf(-a1));
                }
            }
        }
    }
    __syncthreads();

    // ================= QP tail (B buffer reused) =================
    f32x4 (*qC)[256]  = (f32x4(*)[256])Bbuf;              // 36 KB
    f32x4 (*res)[256] = (f32x4(*)[256])(Bbuf + 2304);     // 12 KB, after qC

    const int rq   = tid & 255;         // row within block (0..255)
    const int part = tid >> 8;          // 0..3
    const int R    = blockRow + rq;
    float p0 = lds_p[rq][0];
    float p1 = lds_p[rq][1];

    if (part == 0) {
        float s0 = lds_p[rq][2];
        float s1 = lds_p[rq][3];
        float xr[8];
        const float* xp = x + (R < Btot ? R : 0) * 8;
        #pragma unroll
        for (int c = 0; c < 8; ++c) xr[c] = fmaf(xp[c], stdp[c], meanp[c]);
        float px = xr[0], py = xr[1], th = xr[2], v = xr[3];
        float ox = xr[4], oy = xr[5], oth = xr[6], ov = xr[7];
        float st = __sinf(th),  ct = __cosf(th);
        float so = __sinf(oth), co = __cosf(oth);
        float vs = v * st, vc = v * ct;
        float sps = s0 + s1, ss = s0 * s1;
        float Lf2b = 2.f * v * v;
        #pragma unroll 1
        for (int k = 0; k < 8; ++k) {
            float dx = px - OBX[k], dy = py - OBY[k];
            float bar  = dx * dx + dy * dy - 0.64f;
            float bdot = 2.f * dx * vc + 2.f * dy * vs;
            float gx = 2.f * dx * vs - 2.f * dy * vc;
            float gy = -(2.f * dx * ct + 2.f * dy * st);
            float hk = Lf2b + sps * bdot + ss * bar;
            float ht = hk + 1e-6f * (1.f + fabsf(hk));
            qC[k][rq] = (f32x4){gx, gy, hk, ht};
        }
        {
            float dxo = px - ox, dyo = py - oy;
            float bar_o  = dxo * dxo + dyo * dyo - 0.25f;
            float bdot_o = 2.f * dxo * (vc - ov * co) + 2.f * dyo * (vs - ov * so);
            float Lf2b_o = 2.f * (v * v + ov * ov + 2.f * v * ov * __cosf(th - oth));
            float gx = 2.f * dxo * vs - 2.f * dyo * vc;
            float gy = -(2.f * dxo * ct + 2.f * dyo * st);
            float hk = Lf2b_o + sps * bdot_o + ss * bar_o;
            float ht = hk + 1e-6f * (1.f + fabsf(hk));
            qC[8][rq] = (f32x4){gx, gy, hk, ht};
        }
    }
    __syncthreads();

    // preload the 9 constraints into NAMED registers
    const f32x4 C0 = qC[0][rq], C1 = qC[1][rq], C2 = qC[2][rq];
    const f32x4 C3 = qC[3][rq], C4 = qC[4][rq], C5 = qC[5][rq];
    const f32x4 C6 = qC[6][rq], C7 = qC[7][rq], C8 = qC[8][rq];

    // candidates: 0 unconstrained, 1..9 singles, 10..45 pairs (triu order)
    // 4-way ordered split: [0,12) [12,24) [24,35) [35,46)
    const int c0i = (part == 0) ? 0  : (part == 1) ? 12 : (part == 2) ? 24 : 35;
    const int c1i = (part == 0) ? 12 : (part == 1) ? 24 : (part == 2) ? 35 : 46;
    float bobj = INFINITY;
    float bzx = -p0, bzy = -p1;     // argmin of all-inf -> index 0 -> z0
    #pragma unroll 2
    for (int c = c0i; c < c1i; ++c) {
        float zx, zy;
        bool pre;
        if (c == 0) {
            zx = -p0; zy = -p1; pre = true;
        } else if (c <= 9) {
            f32x4 g = qC[c - 1][rq];                 // one ds_read_b128
            float gg  = g.x * g.x + g.y * g.y;
            float lam = (-(g.x * p0 + g.y * p1) - g.z) / (gg + 1e-12f);
            zx = -p0 - lam * g.x;
            zy = -p1 - lam * g.y;
            pre = (lam >= -1e-8f);
        } else {
            int t = c - 10;
            int pi = unpack4(PI0_, PI1_, PI2_, t);   // scalar, no memory
            int pj = unpack4(PJ0_, PJ1_, PJ2_, t);
            f32x4 gi = qC[pi][rq];                   // two ds_read_b128
            f32x4 gj = qC[pj][rq];
            float det = gi.x * gj.y - gi.y * gj.x;
            bool dok = fabsf(det) > 1e-9f;
            float ds = dok ? det : 1.0f;
            float inv = 1.0f / ds;
            zx = (gi.z * gj.y - gj.z * gi.y) * inv;
            zy = (gi.x * gj.z - gj.x * gi.z) * inv;
            float rx = -(zx + p0), ry = -(zy + p1);
            float li = (gj.y * rx - gj.x * ry) * inv;
            float lj = (gi.x * ry - gi.y * rx) * inv;
            pre = dok && (li >= -1e-8f) && (lj >= -1e-8f);
        }
        bool ok = pre;
        ok = ok && (zx * C0.x + zy * C0.y <= C0.w);
        ok = ok && (zx * C1.x + zy * C1.y <= C1.w);
        ok = ok && (zx * C2.x + zy * C2.y <= C2.w);
        ok = ok && (zx * C3.x + zy * C3.y <= C3.w);
        ok = ok && (zx * C4.x + zy * C4.y <= C4.w);
        ok = ok && (zx * C5.x + zy * C5.y <= C5.w);
        ok = ok && (zx * C6.x + zy * C6.y <= C6.w);
        ok = ok && (zx * C7.x + zy * C7.y <= C7.w);
        ok = ok && (zx * C8.x + zy * C8.y <= C8.w);
        float obj = 0.5f * (zx * zx + zy * zy) + zx * p0 + zy * p1;
        if (ok && obj < bobj) { bobj = obj; bzx = zx; bzy = zy; }
    }

    if (part) {
        res[part - 1][rq] = (f32x4){bobj, bzx, bzy, 0.f};
    }
    __syncthreads();
    if (part == 0) {
        #pragma unroll
        for (int pp = 0; pp < 3; ++pp) {
            f32x4 r = res[pp][rq];
            if (r.x < bobj) { bobj = r.x; bzx = r.y; bzy = r.z; }  // strict <, ordered
        }
        if (R < Btot) {
            f32x2 o2; o2.x = bzx; o2.y = bzy;
            ((f32x2*)out)[R] = o2;
        }
    }
}

extern "C" void kernel_launch(void* const* d_in, const int* in_sizes, int n_in,
                              void* d_out, int out_size, void* d_ws, size_t ws_size,
                              hipStream_t stream) {
    const float* x    = (const float*)d_in[0];
    const float* mean = (const float*)d_in[1];
    const float* stdv = (const float*)d_in[2];
    const float* W1   = (const float*)d_in[3];
    const float* b1   = (const float*)d_in[4];
    const float* W21  = (const float*)d_in[5];
    const float* b21  = (const float*)d_in[6];
    const float* W31  = (const float*)d_in[7];
    const float* b31  = (const float*)d_in[8];
    const float* W22  = (const float*)d_in[9];
    const float* b22  = (const float*)d_in[10];
    const float* W32  = (const float*)d_in[11];
    const float* b32  = (const float*)d_in[12];
    int B = in_sizes[0] / 8;
    float* out = (float*)d_out;
    u32* ws = (u32*)d_ws;

    hipLaunchKernelGGL(prep_kernel, dim3(32), dim3(256), 0, stream, W21, W22, ws);

    hipLaunchKernelGGL(barriernet_kernel, dim3((B + 255) / 256), dim3(1024), 0, stream,
                       x, mean, stdv, W1, b1, b21, W31, b31, b22, W32, b32,
                       ws, out, B);
}